// Round 3
// baseline (356.880 us; speedup 1.0000x reference)
//
#include <hip/hip_runtime.h>
#include <hip/hip_bf16.h>

typedef _Float16 f16x8 __attribute__((ext_vector_type(8)));
typedef float f32x4 __attribute__((ext_vector_type(4)));

#define MFMA16(a, b, c) __builtin_amdgcn_mfma_f32_16x16x32_f16(a, b, c, 0, 0, 0)

__device__ __forceinline__ void load_lds16(const void* g, void* l) {
  __builtin_amdgcn_global_load_lds(
      (__attribute__((address_space(1))) void*)g,
      (__attribute__((address_space(3))) void*)l, 16, 0, 0);
}

// ---------------- f32 -> f16 convert (8 elems / thread / iter) ----------------
__global__ __launch_bounds__(256) void k_cvt16(const float* __restrict__ in,
                                               _Float16* __restrict__ out, int n8) {
  int stride = gridDim.x * blockDim.x;
  for (int i = blockIdx.x * blockDim.x + threadIdx.x; i < n8; i += stride) {
    const float4* p = (const float4*)(in + (size_t)i * 8);
    float4 a = p[0], b = p[1];
    f16x8 v = {(_Float16)a.x, (_Float16)a.y, (_Float16)a.z, (_Float16)a.w,
               (_Float16)b.x, (_Float16)b.y, (_Float16)b.z, (_Float16)b.w};
    *(f16x8*)(out + (size_t)i * 8) = v;
  }
}

// ---------- transpose + convert: in[K][N] f32 -> out[N][K] f16, 64x64 tiles ----------
__global__ __launch_bounds__(256) void k_transpose(const float* __restrict__ in,
                                                   _Float16* __restrict__ out, int K, int N) {
  __shared__ float tile[64][65];
  int k0 = blockIdx.y * 64, n0 = blockIdx.x * 64;
  int t = threadIdx.x;
  {
    int nn = t & 63, kb = t >> 6;
#pragma unroll
    for (int i = 0; i < 16; ++i) {
      int kk = kb + i * 4;
      tile[kk][nn] = in[(size_t)(k0 + kk) * N + n0 + nn];
    }
  }
  __syncthreads();
  {
    int kk = t & 63, nb = t >> 6;
#pragma unroll
    for (int i = 0; i < 16; ++i) {
      int nn = nb + i * 4;
      out[(size_t)(n0 + nn) * K + k0 + kk] = (_Float16)tile[kk][nn];
    }
  }
}

// ---------------- K/V projection: ctxh[616][768] @ W^T -> heads ----------------
// Kg: [B*H][77][64] f16.  Vtg: [B*H][64][128] f16 (transposed, m-padded w/ zeros).
__global__ __launch_bounds__(64) void k_kvproj(const _Float16* __restrict__ ctxh,
                                               const _Float16* __restrict__ Wkt,
                                               const _Float16* __restrict__ Wvt,
                                               _Float16* __restrict__ Kg,
                                               _Float16* __restrict__ Vtg) {
  int mt = blockIdx.x, nt = blockIdx.y;
  int lane = threadIdx.x;
  int l15 = lane & 15, lhi = lane >> 4;
  int arow = mt * 16 + l15;
  if (arow > 615) arow = 615;  // clamp; masked at write
  const _Float16* ap = ctxh + (size_t)arow * 768 + lhi * 8;
  const _Float16* kp = Wkt + (size_t)(nt * 16 + l15) * 768 + lhi * 8;
  const _Float16* vp = Wvt + (size_t)(nt * 16 + l15) * 768 + lhi * 8;
  f32x4 ak = {0.f, 0.f, 0.f, 0.f}, av = {0.f, 0.f, 0.f, 0.f};
#pragma unroll 4
  for (int ks = 0; ks < 24; ++ks) {
    f16x8 a = *(const f16x8*)(ap + ks * 32);
    f16x8 bk = *(const f16x8*)(kp + ks * 32);
    f16x8 bv = *(const f16x8*)(vp + ks * 32);
    ak = MFMA16(a, bk, ak);
    av = MFMA16(a, bv, av);
  }
  int n = nt * 16 + l15, h = n >> 6, d = n & 63;
#pragma unroll
  for (int j = 0; j < 4; ++j) {
    int gm = mt * 16 + lhi * 4 + j;
    if (gm < 616) {
      int b = gm / 77, m = gm - b * 77;
      Kg[((size_t)(b * 16 + h) * 77 + m) * 64 + d] = (_Float16)ak[j];
      Vtg[((size_t)(b * 16 + h) * 64 + d) * 128 + m] = (_Float16)av[j];
    }
  }
}

// ---------------- attention: one block = one (b,h) x 64 query rows ----------------
__global__ __launch_bounds__(256) void k_attn(const _Float16* __restrict__ Qh,
                                              const _Float16* __restrict__ Kg,
                                              const _Float16* __restrict__ Vtg,
                                              _Float16* __restrict__ Out) {
  __shared__ __align__(16) char Kl[80 * 128];       // [m][64 f16], XOR-swizzled
  __shared__ __align__(16) char Vl[64 * 256];       // [d][128 f16], XOR-swizzled
  __shared__ __align__(16) char Pl[4 * 16 * 256];   // per-wave [r][128 f16], swizzled
  int bh = blockIdx.y, b = bh >> 4, h = bh & 15;
  int t = threadIdx.x, wid = t >> 6, lane = t & 63;
  int l15 = lane & 15, lhi = lane >> 4;

  const _Float16* Kgp = Kg + (size_t)bh * (77 * 64);
  const _Float16* Vgp = Vtg + (size_t)bh * (64 * 128);

  // stage K (pad rows 77..79 with zeros)
  for (int idx = t; idx < 640; idx += 256) {
    int m = idx >> 3, c = (idx & 7) * 8;
    f16x8 v = {};
    if (m < 77) v = *(const f16x8*)(Kgp + m * 64 + c);
    *(f16x8*)(Kl + ((m * 128 + c * 2) ^ ((m & 7) << 4))) = v;
  }
  // stage V^T (already zero-padded in global)
  for (int idx = t; idx < 1024; idx += 256) {
    int d = idx >> 4, c = (idx & 15) * 8;
    f16x8 v = *(const f16x8*)(Vgp + d * 128 + c);
    *(f16x8*)(Vl + ((d * 256 + c * 2) ^ ((d & 7) << 4))) = v;
  }
  // zero my wave's P region
  char* myP = Pl + wid * 4096;
#pragma unroll
  for (int i = 0; i < 4; ++i) *(f16x8*)(myP + lane * 64 + i * 16) = f16x8{};
  __syncthreads();

  // Q fragments (direct from global, coalesced 16B)
  int qrow = b * 4096 + blockIdx.x * 64 + wid * 16 + l15;
  const _Float16* qp = Qh + (size_t)qrow * 1024 + h * 64 + lhi * 8;
  f16x8 q0 = *(const f16x8*)qp;
  f16x8 q1 = *(const f16x8*)(qp + 32);

  // scores: D[r][m] ; lane holds m = ct*16 + l15, rows lhi*4+j
  float e[5][4];
  float mx[4] = {-1e30f, -1e30f, -1e30f, -1e30f};
#pragma unroll
  for (int ct = 0; ct < 5; ++ct) {
    int m = ct * 16 + l15;
    int d0b = lhi * 16;
    f16x8 k0 = *(const f16x8*)(Kl + ((m * 128 + d0b) ^ ((m & 7) << 4)));
    f16x8 k1 = *(const f16x8*)(Kl + ((m * 128 + 64 + d0b) ^ ((m & 7) << 4)));
    f32x4 acc = {0.f, 0.f, 0.f, 0.f};
    acc = MFMA16(q0, k0, acc);
    acc = MFMA16(q1, k1, acc);
    bool valid = m < 77;
#pragma unroll
    for (int j = 0; j < 4; ++j) {
      float v = valid ? acc[j] * 0.125f : -1e30f;
      e[ct][j] = v;
      mx[j] = fmaxf(mx[j], v);
    }
  }
#pragma unroll
  for (int off = 1; off < 16; off <<= 1)
#pragma unroll
    for (int j = 0; j < 4; ++j) mx[j] = fmaxf(mx[j], __shfl_xor(mx[j], off, 64));
  float sm[4] = {0.f, 0.f, 0.f, 0.f};
#pragma unroll
  for (int ct = 0; ct < 5; ++ct)
#pragma unroll
    for (int j = 0; j < 4; ++j) {
      float ev = __expf(e[ct][j] - mx[j]);  // invalid (-1e30) -> 0
      e[ct][j] = ev;
      sm[j] += ev;
    }
#pragma unroll
  for (int off = 1; off < 16; off <<= 1)
#pragma unroll
    for (int j = 0; j < 4; ++j) sm[j] += __shfl_xor(sm[j], off, 64);
  float rs[4];
#pragma unroll
  for (int j = 0; j < 4; ++j) rs[j] = 1.0f / sm[j];

  // write P to LDS in A-fragment layout [r][m]
#pragma unroll
  for (int ct = 0; ct < 5; ++ct) {
    int m = ct * 16 + l15;
#pragma unroll
    for (int j = 0; j < 4; ++j) {
      int r = lhi * 4 + j;
      *(_Float16*)(myP + ((r * 256 + m * 2) ^ ((r & 7) << 4))) =
          (_Float16)(e[ct][j] * rs[j]);
    }
  }

  // PV: out[r][d] = sum_m P[r][m] * V[m][d]
  f32x4 o[4] = {{0.f,0.f,0.f,0.f},{0.f,0.f,0.f,0.f},{0.f,0.f,0.f,0.f},{0.f,0.f,0.f,0.f}};
#pragma unroll
  for (int ks = 0; ks < 3; ++ks) {
    int m0b = ks * 64 + lhi * 16;
    f16x8 pa = *(const f16x8*)(myP + ((l15 * 256 + m0b) ^ ((l15 & 7) << 4)));
#pragma unroll
    for (int dt = 0; dt < 4; ++dt) {
      int d = dt * 16 + l15;
      f16x8 vb = *(const f16x8*)(Vl + ((d * 256 + m0b) ^ ((d & 7) << 4)));
      o[dt] = MFMA16(pa, vb, o[dt]);
    }
  }
  _Float16* op = Out + (size_t)(b * 4096 + blockIdx.x * 64 + wid * 16) * 1024 + h * 64;
#pragma unroll
  for (int dt = 0; dt < 4; ++dt)
#pragma unroll
    for (int j = 0; j < 4; ++j) {
      int r = lhi * 4 + j;
      op[(size_t)r * 1024 + dt * 16 + l15] = (_Float16)o[dt][j];
    }
}

// ---------------- m97-style 128x128 GEMM: C = A @ Bt^T ----------------
// A [M][K] f16, Bt [N][K] f16.  FINAL=0: f16 out.  FINAL=1: f32 out + bias.
template <int FINAL>
__global__ __launch_bounds__(256) void k_gemm(const _Float16* __restrict__ A,
                                              const _Float16* __restrict__ Bt,
                                              void* __restrict__ Cout,
                                              const float* __restrict__ bias,
                                              int M, int N, int K) {
  __shared__ __align__(16) char Al[8192];  // [128][32] f16
  __shared__ __align__(16) char Bl[8192];  // [128][32] f16
  int tn = blockIdx.x, tm = blockIdx.y;
  int t = threadIdx.x, wid = t >> 6, lane = t & 63;
  int l15 = lane & 15, lhi = lane >> 4;
  int wr = wid >> 1, wc = wid & 1;
  f32x4 acc[4][4];
#pragma unroll
  for (int i = 0; i < 4; ++i)
#pragma unroll
    for (int j = 0; j < 4; ++j) acc[i][j] = f32x4{0.f, 0.f, 0.f, 0.f};

  int srow = t >> 2;
  int scol = (t & 3) * 8;
  const _Float16* gA0 = A + ((size_t)tm * 128 + srow) * K + scol;
  const _Float16* gA1 = gA0 + (size_t)64 * K;
  const _Float16* gB0 = Bt + ((size_t)tn * 128 + srow) * K + scol;
  const _Float16* gB1 = gB0 + (size_t)64 * K;
  char* lA = Al + wid * 1024;
  char* lB = Bl + wid * 1024;

  int nk = K >> 5;
  for (int ks = 0; ks < nk; ++ks) {
    __syncthreads();
    load_lds16(gA0, lA);
    load_lds16(gA1, lA + 4096);
    load_lds16(gB0, lB);
    load_lds16(gB1, lB + 4096);
    gA0 += 32; gA1 += 32; gB0 += 32; gB1 += 32;
    __syncthreads();
    f16x8 af[4], bf[4];
    int kb = lhi * 16;
#pragma unroll
    for (int mi = 0; mi < 4; ++mi)
      af[mi] = *(const f16x8*)(Al + (wr * 64 + mi * 16 + l15) * 64 + kb);
#pragma unroll
    for (int ni = 0; ni < 4; ++ni)
      bf[ni] = *(const f16x8*)(Bl + (wc * 64 + ni * 16 + l15) * 64 + kb);
#pragma unroll
    for (int mi = 0; mi < 4; ++mi)
#pragma unroll
      for (int ni = 0; ni < 4; ++ni)
        acc[mi][ni] = MFMA16(af[mi], bf[ni], acc[mi][ni]);
  }
  int rb = tm * 128 + wr * 64, cb = tn * 128 + wc * 64;
#pragma unroll
  for (int mi = 0; mi < 4; ++mi)
#pragma unroll
    for (int ni = 0; ni < 4; ++ni)
#pragma unroll
      for (int j = 0; j < 4; ++j) {
        int r = rb + mi * 16 + lhi * 4 + j;
        int c = cb + ni * 16 + l15;
        float v = acc[mi][ni][j];
        if (FINAL) {
          // Reference output dtype is float32 (all-f32 jax math).
          ((float*)Cout)[(size_t)r * N + c] = v + bias[c];
        } else {
          ((_Float16*)Cout)[(size_t)r * N + c] = (_Float16)v;
        }
      }
}

extern "C" void kernel_launch(void* const* d_in, const int* in_sizes, int n_in,
                              void* d_out, int out_size, void* d_ws, size_t ws_size,
                              hipStream_t stream) {
  const float* x   = (const float*)d_in[0];
  const float* ctx = (const float*)d_in[1];
  const float* Wq  = (const float*)d_in[2];
  const float* Wk  = (const float*)d_in[3];
  const float* Wv  = (const float*)d_in[4];
  const float* Wo  = (const float*)d_in[5];
  const float* bo  = (const float*)d_in[6];

  // Workspace layout (78.8 MB). Q-projection (67 MB f16) lives in d_out,
  // which is 134 MB as f32 [32768][1024]; Qh is dead before the final f32
  // GEMM overwrites d_out.
  char* ws = (char*)d_ws;
  _Float16* xh   = (_Float16*)(ws + 0);           // [32768][1024] x-f16; later attnOut
  _Float16* Wqt  = (_Float16*)(ws + 67108864);    // [1024][1024]
  _Float16* Wkt  = (_Float16*)(ws + 69206016);    // [1024][768]
  _Float16* Wvt  = (_Float16*)(ws + 70778880);    // [1024][768]
  _Float16* Wot  = (_Float16*)(ws + 72351744);    // [1024][1024]
  _Float16* ctxh = (_Float16*)(ws + 74448896);    // [616][768]
  _Float16* Kg   = (_Float16*)(ws + 75395072);    // [128][77][64]
  _Float16* Vtg  = (_Float16*)(ws + 76656640);    // [128][64][128]  (end: 78,753,792)
  _Float16* Qh   = (_Float16*)d_out;              // [32768][1024] f16 scratch in d_out

  k_cvt16<<<4096, 256, 0, stream>>>(x, xh, 33554432 / 8);
  k_cvt16<<<231, 256, 0, stream>>>(ctx, ctxh, 473088 / 8);
  k_transpose<<<dim3(16, 16), 256, 0, stream>>>(Wq, Wqt, 1024, 1024);
  k_transpose<<<dim3(16, 12), 256, 0, stream>>>(Wk, Wkt, 768, 1024);
  k_transpose<<<dim3(16, 12), 256, 0, stream>>>(Wv, Wvt, 768, 1024);
  k_transpose<<<dim3(16, 16), 256, 0, stream>>>(Wo, Wot, 1024, 1024);
  hipMemsetAsync(Vtg, 0, 2097152, stream);
  k_kvproj<<<dim3(39, 64), 64, 0, stream>>>(ctxh, Wkt, Wvt, Kg, Vtg);
  // GEMM1: Q projection -> d_out (f16 scratch)
  k_gemm<0><<<dim3(8, 256), 256, 0, stream>>>(xh, Wqt, (void*)Qh, nullptr, 32768, 1024, 1024);
  // attention: reads Qh (d_out), writes attnOut -> xh (x-f16 already consumed)
  k_attn<<<dim3(64, 128), 256, 0, stream>>>(Qh, Kg, Vtg, xh);
  // GEMM2: O projection + bias -> d_out (f32), overwrites Qh scratch
  k_gemm<1><<<dim3(8, 256), 256, 0, stream>>>(xh, Wot, d_out, bo, 32768, 1024, 1024);
}

// Round 4
// 305.563 us; speedup vs baseline: 1.1679x; 1.1679x over previous
//
#include <hip/hip_runtime.h>
#include <hip/hip_bf16.h>

typedef _Float16 f16x8 __attribute__((ext_vector_type(8)));
typedef float f32x4 __attribute__((ext_vector_type(4)));
typedef float f32x16 __attribute__((ext_vector_type(16)));

#define MFMA16(a, b, c) __builtin_amdgcn_mfma_f32_16x16x32_f16(a, b, c, 0, 0, 0)
#define MFMA32(a, b, c) __builtin_amdgcn_mfma_f32_32x32x16_f16(a, b, c, 0, 0, 0)

__device__ __forceinline__ void load_lds16(const void* g, void* l) {
  __builtin_amdgcn_global_load_lds(
      (__attribute__((address_space(1))) void*)g,
      (__attribute__((address_space(3))) void*)l, 16, 0, 0);
}

// ---------------- f32 -> f16 convert (8 elems / thread / iter) ----------------
__global__ __launch_bounds__(256) void k_cvt16(const float* __restrict__ in,
                                               _Float16* __restrict__ out, int n8) {
  int stride = gridDim.x * blockDim.x;
  for (int i = blockIdx.x * blockDim.x + threadIdx.x; i < n8; i += stride) {
    const float4* p = (const float4*)(in + (size_t)i * 8);
    float4 a = p[0], b = p[1];
    f16x8 v = {(_Float16)a.x, (_Float16)a.y, (_Float16)a.z, (_Float16)a.w,
               (_Float16)b.x, (_Float16)b.y, (_Float16)b.z, (_Float16)b.w};
    *(f16x8*)(out + (size_t)i * 8) = v;
  }
}

// ---------- transpose + convert: in[K][N] f32 -> out[N][K] f16, 64x64 tiles ----------
__global__ __launch_bounds__(256) void k_transpose(const float* __restrict__ in,
                                                   _Float16* __restrict__ out, int K, int N) {
  __shared__ float tile[64][65];
  int k0 = blockIdx.y * 64, n0 = blockIdx.x * 64;
  int t = threadIdx.x;
  {
    int nn = t & 63, kb = t >> 6;
#pragma unroll
    for (int i = 0; i < 16; ++i) {
      int kk = kb + i * 4;
      tile[kk][nn] = in[(size_t)(k0 + kk) * N + n0 + nn];
    }
  }
  __syncthreads();
  {
    int kk = t & 63, nb = t >> 6;
#pragma unroll
    for (int i = 0; i < 16; ++i) {
      int nn = nb + i * 4;
      out[(size_t)(n0 + nn) * K + k0 + kk] = (_Float16)tile[kk][nn];
    }
  }
}

// ---------------- K/V projection: ctxh[616][768] @ W^T -> heads ----------------
__global__ __launch_bounds__(64) void k_kvproj(const _Float16* __restrict__ ctxh,
                                               const _Float16* __restrict__ Wkt,
                                               const _Float16* __restrict__ Wvt,
                                               _Float16* __restrict__ Kg,
                                               _Float16* __restrict__ Vtg) {
  int mt = blockIdx.x, nt = blockIdx.y;
  int lane = threadIdx.x;
  int l15 = lane & 15, lhi = lane >> 4;
  int arow = mt * 16 + l15;
  if (arow > 615) arow = 615;  // clamp; masked at write
  const _Float16* ap = ctxh + (size_t)arow * 768 + lhi * 8;
  const _Float16* kp = Wkt + (size_t)(nt * 16 + l15) * 768 + lhi * 8;
  const _Float16* vp = Wvt + (size_t)(nt * 16 + l15) * 768 + lhi * 8;
  f32x4 ak = {0.f, 0.f, 0.f, 0.f}, av = {0.f, 0.f, 0.f, 0.f};
#pragma unroll 4
  for (int ks = 0; ks < 24; ++ks) {
    f16x8 a = *(const f16x8*)(ap + ks * 32);
    f16x8 bk = *(const f16x8*)(kp + ks * 32);
    f16x8 bv = *(const f16x8*)(vp + ks * 32);
    ak = MFMA16(a, bk, ak);
    av = MFMA16(a, bv, av);
  }
  int n = nt * 16 + l15, h = n >> 6, d = n & 63;
#pragma unroll
  for (int j = 0; j < 4; ++j) {
    int gm = mt * 16 + lhi * 4 + j;
    if (gm < 616) {
      int b = gm / 77, m = gm - b * 77;
      Kg[((size_t)(b * 16 + h) * 77 + m) * 64 + d] = (_Float16)ak[j];
      Vtg[((size_t)(b * 16 + h) * 64 + d) * 128 + m] = (_Float16)av[j];
    }
  }
}

// ---------------- attention: one block = one (b,h) x 64 query rows ----------------
__global__ __launch_bounds__(256) void k_attn(const _Float16* __restrict__ Qh,
                                              const _Float16* __restrict__ Kg,
                                              const _Float16* __restrict__ Vtg,
                                              _Float16* __restrict__ Out) {
  __shared__ __align__(16) char Kl[80 * 128];
  __shared__ __align__(16) char Vl[64 * 256];
  __shared__ __align__(16) char Pl[4 * 16 * 256];
  int bh = blockIdx.y, b = bh >> 4, h = bh & 15;
  int t = threadIdx.x, wid = t >> 6, lane = t & 63;
  int l15 = lane & 15, lhi = lane >> 4;

  const _Float16* Kgp = Kg + (size_t)bh * (77 * 64);
  const _Float16* Vgp = Vtg + (size_t)bh * (64 * 128);

  for (int idx = t; idx < 640; idx += 256) {
    int m = idx >> 3, c = (idx & 7) * 8;
    f16x8 v = {};
    if (m < 77) v = *(const f16x8*)(Kgp + m * 64 + c);
    *(f16x8*)(Kl + ((m * 128 + c * 2) ^ ((m & 7) << 4))) = v;
  }
  for (int idx = t; idx < 1024; idx += 256) {
    int d = idx >> 4, c = (idx & 15) * 8;
    f16x8 v = *(const f16x8*)(Vgp + d * 128 + c);
    *(f16x8*)(Vl + ((d * 256 + c * 2) ^ ((d & 7) << 4))) = v;
  }
  char* myP = Pl + wid * 4096;
#pragma unroll
  for (int i = 0; i < 4; ++i) *(f16x8*)(myP + lane * 64 + i * 16) = f16x8{};
  __syncthreads();

  int qrow = b * 4096 + blockIdx.x * 64 + wid * 16 + l15;
  const _Float16* qp = Qh + (size_t)qrow * 1024 + h * 64 + lhi * 8;
  f16x8 q0 = *(const f16x8*)qp;
  f16x8 q1 = *(const f16x8*)(qp + 32);

  float e[5][4];
  float mx[4] = {-1e30f, -1e30f, -1e30f, -1e30f};
#pragma unroll
  for (int ct = 0; ct < 5; ++ct) {
    int m = ct * 16 + l15;
    int d0b = lhi * 16;
    f16x8 k0 = *(const f16x8*)(Kl + ((m * 128 + d0b) ^ ((m & 7) << 4)));
    f16x8 k1 = *(const f16x8*)(Kl + ((m * 128 + 64 + d0b) ^ ((m & 7) << 4)));
    f32x4 acc = {0.f, 0.f, 0.f, 0.f};
    acc = MFMA16(q0, k0, acc);
    acc = MFMA16(q1, k1, acc);
    bool valid = m < 77;
#pragma unroll
    for (int j = 0; j < 4; ++j) {
      float v = valid ? acc[j] * 0.125f : -1e30f;
      e[ct][j] = v;
      mx[j] = fmaxf(mx[j], v);
    }
  }
#pragma unroll
  for (int off = 1; off < 16; off <<= 1)
#pragma unroll
    for (int j = 0; j < 4; ++j) mx[j] = fmaxf(mx[j], __shfl_xor(mx[j], off, 64));
  float sm[4] = {0.f, 0.f, 0.f, 0.f};
#pragma unroll
  for (int ct = 0; ct < 5; ++ct)
#pragma unroll
    for (int j = 0; j < 4; ++j) {
      float ev = __expf(e[ct][j] - mx[j]);
      e[ct][j] = ev;
      sm[j] += ev;
    }
#pragma unroll
  for (int off = 1; off < 16; off <<= 1)
#pragma unroll
    for (int j = 0; j < 4; ++j) sm[j] += __shfl_xor(sm[j], off, 64);
  float rs[4];
#pragma unroll
  for (int j = 0; j < 4; ++j) rs[j] = 1.0f / sm[j];

#pragma unroll
  for (int ct = 0; ct < 5; ++ct) {
    int m = ct * 16 + l15;
#pragma unroll
    for (int j = 0; j < 4; ++j) {
      int r = lhi * 4 + j;
      *(_Float16*)(myP + ((r * 256 + m * 2) ^ ((r & 7) << 4))) =
          (_Float16)(e[ct][j] * rs[j]);
    }
  }

  f32x4 o[4] = {{0.f,0.f,0.f,0.f},{0.f,0.f,0.f,0.f},{0.f,0.f,0.f,0.f},{0.f,0.f,0.f,0.f}};
#pragma unroll
  for (int ks = 0; ks < 3; ++ks) {
    int m0b = ks * 64 + lhi * 16;
    f16x8 pa = *(const f16x8*)(myP + ((l15 * 256 + m0b) ^ ((l15 & 7) << 4)));
#pragma unroll
    for (int dt = 0; dt < 4; ++dt) {
      int d = dt * 16 + l15;
      f16x8 vb = *(const f16x8*)(Vl + ((d * 256 + m0b) ^ ((d & 7) << 4)));
      o[dt] = MFMA16(pa, vb, o[dt]);
    }
  }
  _Float16* op = Out + (size_t)(b * 4096 + blockIdx.x * 64 + wid * 16) * 1024 + h * 64;
#pragma unroll
  for (int dt = 0; dt < 4; ++dt)
#pragma unroll
    for (int j = 0; j < 4; ++j) {
      int r = lhi * 4 + j;
      op[(size_t)r * 1024 + dt * 16 + l15] = (_Float16)o[dt][j];
    }
}

// ============ 256x256 8-phase deep-pipelined GEMM: C = A @ Bt^T ============
// A [M][K] f16, Bt [N][K] f16. BK=64, 512 threads = 8 waves (2M x 4N),
// per-wave 128x64 via mfma_f32_32x32x16_f16. NBUF=2 (even tile->buf0, odd->buf1).
// LDS per buf: A [256][64] f16 (32KB) @ +0, B [256][64] f16 (32KB) @ +32768.
// T2 swizzle: 16B-chunk c stored at c ^ (row&7); applied by pre-swizzling the
// global source of global_load_lds (linear LDS dest) and on ds_read addresses.
// Pipeline: 8 phases / 2 K-tiles per iteration; 2 gloads per phase on a slice
// calendar whose destinations are dead >=1 closing-barrier before the store
// issues; counted s_waitcnt vmcnt(6) at phases 3/7 + barrier publishes each
// K-tile one phase-quad before its first ds_read. vmcnt never 0 in main loop.
template <int FINAL>
__global__ __launch_bounds__(512, 2) void k_gemm2(const _Float16* __restrict__ A,
                                                  const _Float16* __restrict__ Bt,
                                                  void* __restrict__ Cout,
                                                  const float* __restrict__ bias,
                                                  int M, int N, int K) {
  __shared__ __align__(16) char lds[131072];
  const int t = threadIdx.x, wid = t >> 6, lane = t & 63;
  const int wr = wid >> 2, wc = wid & 3;      // 2M x 4N wave grid
  const int l31 = lane & 31, hi = lane >> 5, s7 = lane & 7;

  // T1: bijective XCD swizzle (nwg % 8 == 0), then wg = tm*nTN + tn so each
  // XCD owns contiguous tm panels (A fetched once per panel).
  int nwg = gridDim.x, bid = blockIdx.x;
  int wg = ((nwg & 7) == 0) ? ((bid & 7) * (nwg >> 3) + (bid >> 3)) : bid;
  const int nTN = N >> 8;
  const int tm = wg / nTN, tn = wg % nTN;

  const _Float16* Ag = A + (size_t)tm * 256 * K;
  const _Float16* Bg = Bt + (size_t)tn * 256 * K;
  // per-lane staging source offset (elements): row = +lane>>3, chunk pre-swizzled
  const size_t stg = (size_t)(wid * 8 + (lane >> 3)) * K + (size_t)(((lane & 7) ^ (lane >> 3)) * 8);
  const int dstg = wid * 1024;  // per-wave LDS dest offset (bytes)

  // frag-read bases (row*128 bytes); mf/nf add 32*128=4096 per step
  const char* ArdB = lds + (wr * 128 + l31) * 128;
  const char* BrdB = lds + 32768 + (wc * 64 + l31) * 128;
  const int sw0 = (((0 + hi) ^ s7) << 4);
  const int sw1 = (((2 + hi) ^ s7) << 4);
  const int sw2 = (((4 + hi) ^ s7) << 4);
  const int sw3 = (((6 + hi) ^ s7) << 4);

  f32x16 acc[4][2];
#pragma unroll
  for (int i = 0; i < 4; ++i) { acc[i][0] = f32x16{}; acc[i][1] = f32x16{}; }
  f16x8 af0, af1, af2, af3;
  f16x8 b00, b01, b02, b03, b10, b11, b12, b13;

#define STG_A(T, RB) load_lds16(Ag + stg + (size_t)(RB) * K + (T) * 64, \
                                lds + ((T) & 1) * 65536 + (RB) * 128 + dstg)
#define STG_B(T, RB) load_lds16(Bg + stg + (size_t)(RB) * K + (T) * 64, \
                                lds + ((T) & 1) * 65536 + 32768 + (RB) * 128 + dstg)
#define RD_A(BUF, MF) { const char* p_ = ArdB + (BUF) * 65536 + (MF) * 4096;      \
    af0 = *(const f16x8*)(p_ + sw0); af1 = *(const f16x8*)(p_ + sw1);             \
    af2 = *(const f16x8*)(p_ + sw2); af3 = *(const f16x8*)(p_ + sw3); }
#define RD_B(BUF) { const char* q_ = BrdB + (BUF) * 65536;                        \
    b00 = *(const f16x8*)(q_ + sw0); b01 = *(const f16x8*)(q_ + sw1);             \
    b02 = *(const f16x8*)(q_ + sw2); b03 = *(const f16x8*)(q_ + sw3);             \
    b10 = *(const f16x8*)(q_ + 4096 + sw0); b11 = *(const f16x8*)(q_ + 4096 + sw1); \
    b12 = *(const f16x8*)(q_ + 4096 + sw2); b13 = *(const f16x8*)(q_ + 4096 + sw3); }
#define MM(MF) { __builtin_amdgcn_s_setprio(1);                                   \
    acc[MF][0] = MFMA32(af0, b00, acc[MF][0]);                                    \
    acc[MF][1] = MFMA32(af0, b10, acc[MF][1]);                                    \
    acc[MF][0] = MFMA32(af1, b01, acc[MF][0]);                                    \
    acc[MF][1] = MFMA32(af1, b11, acc[MF][1]);                                    \
    acc[MF][0] = MFMA32(af2, b02, acc[MF][0]);                                    \
    acc[MF][1] = MFMA32(af2, b12, acc[MF][1]);                                    \
    acc[MF][0] = MFMA32(af3, b03, acc[MF][0]);                                    \
    acc[MF][1] = MFMA32(af3, b13, acc[MF][1]);                                    \
    __builtin_amdgcn_s_setprio(0); }
#define VM6 asm volatile("s_waitcnt vmcnt(6)" ::: "memory")
#define VM0 asm volatile("s_waitcnt vmcnt(0)" ::: "memory")
#define BAR __builtin_amdgcn_s_barrier()

  const int nT = K >> 6;        // K-tiles (16 for K=1024); must be even
  const int nIter = (nT >> 1) - 1;

  // ---- prologue: tile0 full; tile1 B + A slices {0,128}; newest 6 = tile1 part
  STG_B(0, 0); STG_B(0, 64); STG_B(0, 128); STG_B(0, 192);
  STG_A(0, 0); STG_A(0, 64); STG_A(0, 128); STG_A(0, 192);
  STG_B(1, 0); STG_B(1, 64);
  STG_A(1, 0); STG_A(1, 128);
  STG_B(1, 128); STG_B(1, 192);
  VM6; BAR;

  for (int i = 0; i < nIter; ++i) {
    const int t0 = 2 * i;
    // p0: tile t0 (buf0) B + mf0 | stage A(t0+1) slices {64,192}
    RD_B(0); RD_A(0, 0); STG_A(t0 + 1, 64); STG_A(t0 + 1, 192); BAR; MM(0); BAR;
    // p1 | stage B(t0+2) {0,64}
    RD_A(0, 1); STG_B(t0 + 2, 0); STG_B(t0 + 2, 64); BAR; MM(1); BAR;
    // p2 | stage A(t0+2) {0,128}
    RD_A(0, 2); STG_A(t0 + 2, 0); STG_A(t0 + 2, 128); BAR; MM(2); BAR;
    // p3 | stage B(t0+2) {128,192}; vmcnt(6) publishes tile t0+1
    RD_A(0, 3); STG_B(t0 + 2, 128); STG_B(t0 + 2, 192); VM6; BAR; MM(3); BAR;
    // p4: tile t0+1 (buf1) B + mf0 | stage A(t0+2) {64,192}
    RD_B(1); RD_A(1, 0); STG_A(t0 + 2, 64); STG_A(t0 + 2, 192); BAR; MM(0); BAR;
    // p5 | stage B(t0+3) {0,64}
    RD_A(1, 1); STG_B(t0 + 3, 0); STG_B(t0 + 3, 64); BAR; MM(1); BAR;
    // p6 | stage A(t0+3) {0,128}
    RD_A(1, 2); STG_A(t0 + 3, 0); STG_A(t0 + 3, 128); BAR; MM(2); BAR;
    // p7 | stage B(t0+3) {128,192}; vmcnt(6) publishes tile t0+2
    RD_A(1, 3); STG_B(t0 + 3, 128); STG_B(t0 + 3, 192); VM6; BAR; MM(3); BAR;
  }
  // ---- epilogue: tiles nT-2 (buf0), nT-1 (buf1); drain 2 -> 0 at p3
  RD_B(0); RD_A(0, 0); STG_A(nT - 1, 64); STG_A(nT - 1, 192); BAR; MM(0); BAR;
  RD_A(0, 1); BAR; MM(1); BAR;
  RD_A(0, 2); BAR; MM(2); BAR;
  RD_A(0, 3); VM0; BAR; MM(3); BAR;
  RD_B(1); RD_A(1, 0); BAR; MM(0); BAR;
  RD_A(1, 1); BAR; MM(1); BAR;
  RD_A(1, 2); BAR; MM(2); BAR;
  RD_A(1, 3); BAR; MM(3); BAR;

  // ---- C write: 32x32 C-layout col=lane&31, row=(reg&3)+8*(reg>>2)+4*(lane>>5)
  const long rbase = (long)tm * 256 + wr * 128;
  const int cbase = tn * 256 + wc * 64;
#pragma unroll
  for (int mf = 0; mf < 4; ++mf)
#pragma unroll
    for (int nf = 0; nf < 2; ++nf) {
      int c = cbase + nf * 32 + l31;
      float bv = FINAL ? bias[c] : 0.f;
#pragma unroll
      for (int reg = 0; reg < 16; ++reg) {
        long r = rbase + mf * 32 + (reg & 3) + ((reg >> 2) << 3) + (hi << 2);
        float v = acc[mf][nf][reg];
        if (FINAL) ((float*)Cout)[r * N + c] = v + bv;
        else ((_Float16*)Cout)[r * N + c] = (_Float16)v;
      }
    }
#undef STG_A
#undef STG_B
#undef RD_A
#undef RD_B
#undef MM
#undef VM6
#undef VM0
#undef BAR
}

extern "C" void kernel_launch(void* const* d_in, const int* in_sizes, int n_in,
                              void* d_out, int out_size, void* d_ws, size_t ws_size,
                              hipStream_t stream) {
  const float* x   = (const float*)d_in[0];
  const float* ctx = (const float*)d_in[1];
  const float* Wq  = (const float*)d_in[2];
  const float* Wk  = (const float*)d_in[3];
  const float* Wv  = (const float*)d_in[4];
  const float* Wo  = (const float*)d_in[5];
  const float* bo  = (const float*)d_in[6];

  char* ws = (char*)d_ws;
  _Float16* xh   = (_Float16*)(ws + 0);           // [32768][1024] x-f16; later attnOut
  _Float16* Wqt  = (_Float16*)(ws + 67108864);    // [1024][1024]
  _Float16* Wkt  = (_Float16*)(ws + 69206016);    // [1024][768]
  _Float16* Wvt  = (_Float16*)(ws + 70778880);    // [1024][768]
  _Float16* Wot  = (_Float16*)(ws + 72351744);    // [1024][1024]
  _Float16* ctxh = (_Float16*)(ws + 74448896);    // [616][768]
  _Float16* Kg   = (_Float16*)(ws + 75395072);    // [128][77][64]
  _Float16* Vtg  = (_Float16*)(ws + 76656640);    // [128][64][128]
  _Float16* Qh   = (_Float16*)d_out;              // [32768][1024] f16 scratch in d_out

  k_cvt16<<<4096, 256, 0, stream>>>(x, xh, 33554432 / 8);
  k_cvt16<<<231, 256, 0, stream>>>(ctx, ctxh, 473088 / 8);
  k_transpose<<<dim3(16, 16), 256, 0, stream>>>(Wq, Wqt, 1024, 1024);
  k_transpose<<<dim3(16, 12), 256, 0, stream>>>(Wk, Wkt, 768, 1024);
  k_transpose<<<dim3(16, 12), 256, 0, stream>>>(Wv, Wvt, 768, 1024);
  k_transpose<<<dim3(16, 16), 256, 0, stream>>>(Wo, Wot, 1024, 1024);
  hipMemsetAsync(Vtg, 0, 2097152, stream);
  k_kvproj<<<dim3(39, 64), 64, 0, stream>>>(ctxh, Wkt, Wvt, Kg, Vtg);
  // GEMM1: Q projection -> d_out (f16 scratch): grid = (32768/256)*(1024/256)=512
  k_gemm2<0><<<dim3(512), dim3(512), 0, stream>>>(xh, Wqt, (void*)Qh, nullptr, 32768, 1024, 1024);
  // attention: reads Qh (d_out), writes attnOut -> xh
  k_attn<<<dim3(64, 128), 256, 0, stream>>>(Qh, Kg, Vtg, xh);
  // GEMM2: O projection + bias -> d_out (f32)
  k_gemm2<1><<<dim3(512), dim3(512), 0, stream>>>(xh, Wot, d_out, bo, 32768, 1024, 1024);
}

// Round 5
// 291.904 us; speedup vs baseline: 1.2226x; 1.0468x over previous
//
#include <hip/hip_runtime.h>
#include <hip/hip_bf16.h>

typedef _Float16 f16x8 __attribute__((ext_vector_type(8)));
typedef float f32x4 __attribute__((ext_vector_type(4)));

#define MFMA16(a, b, c) __builtin_amdgcn_mfma_f32_16x16x32_f16(a, b, c, 0, 0, 0)

__device__ __forceinline__ void load_lds16(const void* g, void* l) {
  __builtin_amdgcn_global_load_lds(
      (__attribute__((address_space(1))) void*)g,
      (__attribute__((address_space(3))) void*)l, 16, 0, 0);
}

// ---------------- f32 -> f16 convert (8 elems / thread / iter) ----------------
__global__ __launch_bounds__(256) void k_cvt16(const float* __restrict__ in,
                                               _Float16* __restrict__ out, int n8) {
  int stride = gridDim.x * blockDim.x;
  for (int i = blockIdx.x * blockDim.x + threadIdx.x; i < n8; i += stride) {
    const float4* p = (const float4*)(in + (size_t)i * 8);
    float4 a = p[0], b = p[1];
    f16x8 v = {(_Float16)a.x, (_Float16)a.y, (_Float16)a.z, (_Float16)a.w,
               (_Float16)b.x, (_Float16)b.y, (_Float16)b.z, (_Float16)b.w};
    *(f16x8*)(out + (size_t)i * 8) = v;
  }
}

// ---------- transpose + convert: in[K][N] f32 -> out[N][K] f16, 64x64 tiles ----------
__global__ __launch_bounds__(256) void k_transpose(const float* __restrict__ in,
                                                   _Float16* __restrict__ out, int K, int N) {
  __shared__ float tile[64][65];
  int k0 = blockIdx.y * 64, n0 = blockIdx.x * 64;
  int t = threadIdx.x;
  {
    int nn = t & 63, kb = t >> 6;
#pragma unroll
    for (int i = 0; i < 16; ++i) {
      int kk = kb + i * 4;
      tile[kk][nn] = in[(size_t)(k0 + kk) * N + n0 + nn];
    }
  }
  __syncthreads();
  {
    int kk = t & 63, nb = t >> 6;
#pragma unroll
    for (int i = 0; i < 16; ++i) {
      int nn = nb + i * 4;
      out[(size_t)(n0 + nn) * K + k0 + kk] = (_Float16)tile[kk][nn];
    }
  }
}

// ---------------- K/V projection: ctxh[616][768] @ W^T -> heads ----------------
__global__ __launch_bounds__(64) void k_kvproj(const _Float16* __restrict__ ctxh,
                                               const _Float16* __restrict__ Wkt,
                                               const _Float16* __restrict__ Wvt,
                                               _Float16* __restrict__ Kg,
                                               _Float16* __restrict__ Vtg) {
  int mt = blockIdx.x, nt = blockIdx.y;
  int lane = threadIdx.x;
  int l15 = lane & 15, lhi = lane >> 4;
  int arow = mt * 16 + l15;
  if (arow > 615) arow = 615;  // clamp; masked at write
  const _Float16* ap = ctxh + (size_t)arow * 768 + lhi * 8;
  const _Float16* kp = Wkt + (size_t)(nt * 16 + l15) * 768 + lhi * 8;
  const _Float16* vp = Wvt + (size_t)(nt * 16 + l15) * 768 + lhi * 8;
  f32x4 ak = {0.f, 0.f, 0.f, 0.f}, av = {0.f, 0.f, 0.f, 0.f};
#pragma unroll 4
  for (int ks = 0; ks < 24; ++ks) {
    f16x8 a = *(const f16x8*)(ap + ks * 32);
    f16x8 bk = *(const f16x8*)(kp + ks * 32);
    f16x8 bv = *(const f16x8*)(vp + ks * 32);
    ak = MFMA16(a, bk, ak);
    av = MFMA16(a, bv, av);
  }
  int n = nt * 16 + l15, h = n >> 6, d = n & 63;
#pragma unroll
  for (int j = 0; j < 4; ++j) {
    int gm = mt * 16 + lhi * 4 + j;
    if (gm < 616) {
      int b = gm / 77, m = gm - b * 77;
      Kg[((size_t)(b * 16 + h) * 77 + m) * 64 + d] = (_Float16)ak[j];
      Vtg[((size_t)(b * 16 + h) * 64 + d) * 128 + m] = (_Float16)av[j];
    }
  }
}

// ---------------- attention: one block = one (b,h) x 64 query rows ----------------
__global__ __launch_bounds__(256) void k_attn(const _Float16* __restrict__ Qh,
                                              const _Float16* __restrict__ Kg,
                                              const _Float16* __restrict__ Vtg,
                                              _Float16* __restrict__ Out) {
  __shared__ __align__(16) char Kl[80 * 128];
  __shared__ __align__(16) char Vl[64 * 256];
  __shared__ __align__(16) char Pl[4 * 16 * 256];
  int bh = blockIdx.y, b = bh >> 4, h = bh & 15;
  int t = threadIdx.x, wid = t >> 6, lane = t & 63;
  int l15 = lane & 15, lhi = lane >> 4;

  const _Float16* Kgp = Kg + (size_t)bh * (77 * 64);
  const _Float16* Vgp = Vtg + (size_t)bh * (64 * 128);

  for (int idx = t; idx < 640; idx += 256) {
    int m = idx >> 3, c = (idx & 7) * 8;
    f16x8 v = {};
    if (m < 77) v = *(const f16x8*)(Kgp + m * 64 + c);
    *(f16x8*)(Kl + ((m * 128 + c * 2) ^ ((m & 7) << 4))) = v;
  }
  for (int idx = t; idx < 1024; idx += 256) {
    int d = idx >> 4, c = (idx & 15) * 8;
    f16x8 v = *(const f16x8*)(Vgp + d * 128 + c);
    *(f16x8*)(Vl + ((d * 256 + c * 2) ^ ((d & 7) << 4))) = v;
  }
  char* myP = Pl + wid * 4096;
#pragma unroll
  for (int i = 0; i < 4; ++i) *(f16x8*)(myP + lane * 64 + i * 16) = f16x8{};
  __syncthreads();

  int qrow = b * 4096 + blockIdx.x * 64 + wid * 16 + l15;
  const _Float16* qp = Qh + (size_t)qrow * 1024 + h * 64 + lhi * 8;
  f16x8 q0 = *(const f16x8*)qp;
  f16x8 q1 = *(const f16x8*)(qp + 32);

  float e[5][4];
  float mx[4] = {-1e30f, -1e30f, -1e30f, -1e30f};
#pragma unroll
  for (int ct = 0; ct < 5; ++ct) {
    int m = ct * 16 + l15;
    int d0b = lhi * 16;
    f16x8 k0 = *(const f16x8*)(Kl + ((m * 128 + d0b) ^ ((m & 7) << 4)));
    f16x8 k1 = *(const f16x8*)(Kl + ((m * 128 + 64 + d0b) ^ ((m & 7) << 4)));
    f32x4 acc = {0.f, 0.f, 0.f, 0.f};
    acc = MFMA16(q0, k0, acc);
    acc = MFMA16(q1, k1, acc);
    bool valid = m < 77;
#pragma unroll
    for (int j = 0; j < 4; ++j) {
      float v = valid ? acc[j] * 0.125f : -1e30f;
      e[ct][j] = v;
      mx[j] = fmaxf(mx[j], v);
    }
  }
#pragma unroll
  for (int off = 1; off < 16; off <<= 1)
#pragma unroll
    for (int j = 0; j < 4; ++j) mx[j] = fmaxf(mx[j], __shfl_xor(mx[j], off, 64));
  float sm[4] = {0.f, 0.f, 0.f, 0.f};
#pragma unroll
  for (int ct = 0; ct < 5; ++ct)
#pragma unroll
    for (int j = 0; j < 4; ++j) {
      float ev = __expf(e[ct][j] - mx[j]);
      e[ct][j] = ev;
      sm[j] += ev;
    }
#pragma unroll
  for (int off = 1; off < 16; off <<= 1)
#pragma unroll
    for (int j = 0; j < 4; ++j) sm[j] += __shfl_xor(sm[j], off, 64);
  float rs[4];
#pragma unroll
  for (int j = 0; j < 4; ++j) rs[j] = 1.0f / sm[j];

#pragma unroll
  for (int ct = 0; ct < 5; ++ct) {
    int m = ct * 16 + l15;
#pragma unroll
    for (int j = 0; j < 4; ++j) {
      int r = lhi * 4 + j;
      *(_Float16*)(myP + ((r * 256 + m * 2) ^ ((r & 7) << 4))) =
          (_Float16)(e[ct][j] * rs[j]);
    }
  }

  f32x4 o[4] = {{0.f,0.f,0.f,0.f},{0.f,0.f,0.f,0.f},{0.f,0.f,0.f,0.f},{0.f,0.f,0.f,0.f}};
#pragma unroll
  for (int ks = 0; ks < 3; ++ks) {
    int m0b = ks * 64 + lhi * 16;
    f16x8 pa = *(const f16x8*)(myP + ((l15 * 256 + m0b) ^ ((l15 & 7) << 4)));
#pragma unroll
    for (int dt = 0; dt < 4; ++dt) {
      int d = dt * 16 + l15;
      f16x8 vb = *(const f16x8*)(Vl + ((d * 256 + m0b) ^ ((d & 7) << 4)));
      o[dt] = MFMA16(pa, vb, o[dt]);
    }
  }
  _Float16* op = Out + (size_t)(b * 4096 + blockIdx.x * 64 + wid * 16) * 1024 + h * 64;
#pragma unroll
  for (int dt = 0; dt < 4; ++dt)
#pragma unroll
    for (int j = 0; j < 4; ++j) {
      int r = lhi * 4 + j;
      op[(size_t)r * 1024 + dt * 16 + l15] = (_Float16)o[dt][j];
    }
}

// ============ 256x256 GEMM, m201 port: 16x16x32 frags + st_16x32 swizzle ============
// A [M][K] f16, Bt [N][K] f16. BK=64 (128-B rows), 512 thr = 8 waves (2M x 4N),
// per-wave C = 128x64 = 8 m-frags x 4 n-frags of 16x16. 4 phases per K-tile,
// 16 MFMA16 per phase (one C-quadrant: mh x nh x kk = 4x2x2).
// st_16x32 swizzle: stored_byte = byte ^ (((byte>>9)&1)<<5)  (bit9 = row bit 2).
// Applied via inverse-swizzled GLOBAL source for global_load_lds (linear dest)
// and the same XOR on ds_read addresses (both-sides involution).
// Staging calendar (2 gloads/phase, tile tau+2 into tau's buffer after slices die):
//   q0: A(tau+1,{64,192})   [other buf]
//   q1: A(tau+2,{0,128})    [dead after q0]
//   q2: B(tau+2,{0,64})     [dead after q1]
//   q3: B(tau+2,{128,192})  [dead after q1]; vmcnt(6); barrier publishes tau+1
template <int FINAL>
__global__ __launch_bounds__(512, 2) void k_gemm3(const _Float16* __restrict__ A,
                                                  const _Float16* __restrict__ Bt,
                                                  void* __restrict__ Cout,
                                                  const float* __restrict__ bias,
                                                  int M, int N, int K) {
  __shared__ __align__(16) char lds[131072];
  const int t = threadIdx.x, wid = t >> 6, lane = t & 63;
  const int wr = wid >> 2, wc = wid & 3;  // 2M x 4N wave grid
  const int l15 = lane & 15, lhi = lane >> 4;

  // T1: bijective XCD swizzle (nwg % 8 == 0)
  int nwg = gridDim.x, bid = blockIdx.x;
  int wg = ((nwg & 7) == 0) ? ((bid & 7) * (nwg >> 3) + (bid >> 3)) : bid;
  const int nTN = N >> 8;
  const int tm = wg / nTN, tn = wg % nTN;

  const _Float16* Ag = A + (size_t)tm * 256 * K;
  const _Float16* Bg = Bt + (size_t)tn * 256 * K;
  // staging source: row = wid*8 + lane>>3 (+RB), chunk inverse-swizzled by dest bit9
  const size_t stg = (size_t)(wid * 8 + (lane >> 3)) * K +
                     (size_t)(((lane & 7) ^ (((lane >> 5) & 1) << 1)) * 8);
  const int dstg = wid * 1024;

  // ds_read swizzle: chunk ^= ((row>>2)&1)<<1 ; row = ...16-aligned... + l15
  const int xb = ((l15 >> 2) & 1) << 1;
  const int aoff = wr * 16384 + l15 * 128 + ((lhi ^ xb) << 4);           // + mh*8192 + mf*2048 + kk*64
  const int boff = 32768 + wc * 8192 + l15 * 128 + ((lhi ^ xb) << 4);    // + nh*4096 + nf2*2048 + kk*64

  f32x4 acc[8][4];
#pragma unroll
  for (int i = 0; i < 8; ++i)
#pragma unroll
    for (int j = 0; j < 4; ++j) acc[i][j] = f32x4{0.f, 0.f, 0.f, 0.f};
  f16x8 a[4][2], b0[2][2], b1[2][2];

#define STG_A(T, RB) load_lds16(Ag + stg + (size_t)(RB) * K + (T) * 64, \
                                lds + ((T) & 1) * 65536 + (RB) * 128 + dstg)
#define STG_B(T, RB) load_lds16(Bg + stg + (size_t)(RB) * K + (T) * 64, \
                                lds + ((T) & 1) * 65536 + 32768 + (RB) * 128 + dstg)
#define RD_A(BUF, MH) { const char* p_ = lds + (BUF) * 65536 + aoff + (MH) * 8192;  \
    _Pragma("unroll") for (int mf = 0; mf < 4; ++mf)                                \
      _Pragma("unroll") for (int kk = 0; kk < 2; ++kk)                              \
        a[mf][kk] = *(const f16x8*)(p_ + mf * 2048 + kk * 64); }
#define RD_B(BUF, NH, BREG) { const char* q_ = lds + (BUF) * 65536 + boff + (NH) * 4096; \
    _Pragma("unroll") for (int nf = 0; nf < 2; ++nf)                                \
      _Pragma("unroll") for (int kk = 0; kk < 2; ++kk)                              \
        BREG[nf][kk] = *(const f16x8*)(q_ + nf * 2048 + kk * 64); }
#define MM(MH, NH, BREG) { __builtin_amdgcn_s_setprio(1);                           \
    _Pragma("unroll") for (int mf = 0; mf < 4; ++mf)                                \
      _Pragma("unroll") for (int nf = 0; nf < 2; ++nf)                              \
        _Pragma("unroll") for (int kk = 0; kk < 2; ++kk)                            \
          acc[(MH)*4+mf][(NH)*2+nf] = MFMA16(a[mf][kk], BREG[nf][kk],               \
                                             acc[(MH)*4+mf][(NH)*2+nf]);            \
    __builtin_amdgcn_s_setprio(0); }
#define VM6 asm volatile("s_waitcnt vmcnt(6)" ::: "memory")
#define VM0 asm volatile("s_waitcnt vmcnt(0)" ::: "memory")
#define BAR __builtin_amdgcn_s_barrier()

  const int nT = K >> 6;  // 16 for K=1024 (even, >= 4)

  // ---- prologue: tile0 (8) + tile1 partial (A{0,128}, B all) = 14 in flight
  STG_A(0, 0); STG_A(0, 64); STG_A(0, 128); STG_A(0, 192);
  STG_B(0, 0); STG_B(0, 64); STG_B(0, 128); STG_B(0, 192);
  STG_A(1, 0); STG_A(1, 128);
  STG_B(1, 0); STG_B(1, 64); STG_B(1, 128); STG_B(1, 192);
  asm volatile("s_waitcnt vmcnt(6)" ::: "memory");  // retire tile0's 8
  BAR;

  const int nPair = (nT - 2) >> 1;  // main tiles 0..nT-3, two per iteration
  for (int i = 0; i < nPair; ++i) {
    const int t0 = 2 * i;
    // ---- tile t0 (buf0)
    RD_B(0, 0, b0); RD_A(0, 0); STG_A(t0 + 1, 64); STG_A(t0 + 1, 192); BAR; MM(0, 0, b0); BAR;
    RD_B(0, 1, b1); STG_A(t0 + 2, 0); STG_A(t0 + 2, 128); BAR; MM(0, 1, b1); BAR;
    RD_A(0, 1); STG_B(t0 + 2, 0); STG_B(t0 + 2, 64); BAR; MM(1, 1, b1); BAR;
    STG_B(t0 + 2, 128); STG_B(t0 + 2, 192); VM6; BAR; MM(1, 0, b0); BAR;
    // ---- tile t0+1 (buf1)
    RD_B(1, 0, b0); RD_A(1, 0); STG_A(t0 + 2, 64); STG_A(t0 + 2, 192); BAR; MM(0, 0, b0); BAR;
    RD_B(1, 1, b1); STG_A(t0 + 3, 0); STG_A(t0 + 3, 128); BAR; MM(0, 1, b1); BAR;
    RD_A(1, 1); STG_B(t0 + 3, 0); STG_B(t0 + 3, 64); BAR; MM(1, 1, b1); BAR;
    STG_B(t0 + 3, 128); STG_B(t0 + 3, 192); VM6; BAR; MM(1, 0, b0); BAR;
  }
  // ---- epilogue: tile nT-2 (buf0) — finish staging tile nT-1, drain to 0
  RD_B(0, 0, b0); RD_A(0, 0); STG_A(nT - 1, 64); STG_A(nT - 1, 192); BAR; MM(0, 0, b0); BAR;
  RD_B(0, 1, b1); BAR; MM(0, 1, b1); BAR;
  RD_A(0, 1); BAR; MM(1, 1, b1); BAR;
  VM0; BAR; MM(1, 0, b0); BAR;
  // ---- tile nT-1 (buf1)
  RD_B(1, 0, b0); RD_A(1, 0); BAR; MM(0, 0, b0); BAR;
  RD_B(1, 1, b1); BAR; MM(0, 1, b1); BAR;
  RD_A(1, 1); BAR; MM(1, 1, b1); BAR;
  MM(1, 0, b0);

  // ---- C write: 16x16 C-layout col = l15, row = lhi*4 + reg (verified m89)
  const long rbase = (long)tm * 256 + wr * 128;
  const int cbase = tn * 256 + wc * 64;
#pragma unroll
  for (int mf = 0; mf < 8; ++mf)
#pragma unroll
    for (int nf = 0; nf < 4; ++nf) {
      int c = cbase + nf * 16 + l15;
      float bv = FINAL ? bias[c] : 0.f;
#pragma unroll
      for (int j = 0; j < 4; ++j) {
        long r = rbase + mf * 16 + lhi * 4 + j;
        float v = acc[mf][nf][j];
        if (FINAL) ((float*)Cout)[r * N + c] = v + bv;
        else ((_Float16*)Cout)[r * N + c] = (_Float16)v;
      }
    }
#undef STG_A
#undef STG_B
#undef RD_A
#undef RD_B
#undef MM
#undef VM6
#undef VM0
#undef BAR
}

extern "C" void kernel_launch(void* const* d_in, const int* in_sizes, int n_in,
                              void* d_out, int out_size, void* d_ws, size_t ws_size,
                              hipStream_t stream) {
  const float* x   = (const float*)d_in[0];
  const float* ctx = (const float*)d_in[1];
  const float* Wq  = (const float*)d_in[2];
  const float* Wk  = (const float*)d_in[3];
  const float* Wv  = (const float*)d_in[4];
  const float* Wo  = (const float*)d_in[5];
  const float* bo  = (const float*)d_in[6];

  char* ws = (char*)d_ws;
  _Float16* xh   = (_Float16*)(ws + 0);           // [32768][1024] x-f16; later attnOut
  _Float16* Wqt  = (_Float16*)(ws + 67108864);    // [1024][1024]
  _Float16* Wkt  = (_Float16*)(ws + 69206016);    // [1024][768]
  _Float16* Wvt  = (_Float16*)(ws + 70778880);    // [1024][768]
  _Float16* Wot  = (_Float16*)(ws + 72351744);    // [1024][1024]
  _Float16* ctxh = (_Float16*)(ws + 74448896);    // [616][768]
  _Float16* Kg   = (_Float16*)(ws + 75395072);    // [128][77][64]
  _Float16* Vtg  = (_Float16*)(ws + 76656640);    // [128][64][128]
  _Float16* Qh   = (_Float16*)d_out;              // [32768][1024] f16 scratch in d_out

  k_cvt16<<<4096, 256, 0, stream>>>(x, xh, 33554432 / 8);
  k_cvt16<<<231, 256, 0, stream>>>(ctx, ctxh, 473088 / 8);
  k_transpose<<<dim3(16, 16), 256, 0, stream>>>(Wq, Wqt, 1024, 1024);
  k_transpose<<<dim3(16, 12), 256, 0, stream>>>(Wk, Wkt, 768, 1024);
  k_transpose<<<dim3(16, 12), 256, 0, stream>>>(Wv, Wvt, 768, 1024);
  k_transpose<<<dim3(16, 16), 256, 0, stream>>>(Wo, Wot, 1024, 1024);
  hipMemsetAsync(Vtg, 0, 2097152, stream);
  k_kvproj<<<dim3(39, 64), 64, 0, stream>>>(ctxh, Wkt, Wvt, Kg, Vtg);
  // GEMM1: Q projection -> d_out (f16 scratch); grid 512 (%8==0 for T1)
  k_gemm3<0><<<dim3(512), dim3(512), 0, stream>>>(xh, Wqt, (void*)Qh, nullptr, 32768, 1024, 1024);
  // attention: reads Qh (d_out), writes attnOut -> xh
  k_attn<<<dim3(64, 128), 256, 0, stream>>>(Qh, Kg, Vtg, xh);
  // GEMM2: O projection + bias -> d_out (f32)
  k_gemm3<1><<<dim3(512), dim3(512), 0, stream>>>(xh, Wot, d_out, bo, 32768, 1024, 1024);
}